// Round 1
// baseline (193.346 us; speedup 1.0000x reference)
//
#include <hip/hip_runtime.h>

#define BB   128
#define DD   1024
#define RR   36
#define PP   8
#define NNEG 16
#define PRR  4

// ws float layout: [0]=obj [1]=attr [2]=rel [3]=comp [4]=sent ; [16..400)=diag[3][128]
#define WS_DIAG 16

__global__ __launch_bounds__(64) void k_zero(float* __restrict__ ws) {
    int t = threadIdx.x;
    if (t < 8) ws[t] = 0.0f;
}

__global__ __launch_bounds__(64) void k_diag(const float* __restrict__ img,
                                             const float* __restrict__ sent,
                                             const float* __restrict__ comp,
                                             const float* __restrict__ rel,
                                             const int*   __restrict__ relidx,
                                             float* __restrict__ ws) {
    const int i = blockIdx.x, t = blockIdx.y, lane = threadIdx.x;
    const float* x;
    if (t == 0)      x = sent + (size_t)i * DD;
    else if (t == 1) x = comp + (size_t)i * DD;
    else             x = rel + ((size_t)i * PRR + relidx[i]) * DD;
    const float* a = img + (size_t)i * DD;
    float acc = 0.0f;
#pragma unroll
    for (int k = 0; k < 4; ++k) {
        float4 va = *reinterpret_cast<const float4*>(a + lane * 4 + k * 256);
        float4 vb = *reinterpret_cast<const float4*>(x + lane * 4 + k * 256);
        acc += va.x * vb.x + va.y * vb.y + va.z * vb.z + va.w * vb.w;
    }
#pragma unroll
    for (int off = 32; off > 0; off >>= 1) acc += __shfl_down(acc, off);
    if (lane == 0) ws[WS_DIAG + t * BB + i] = acc;
}

// scores tile (16x16) per block; grid (8,8,3); 256 threads = 16x16
__global__ __launch_bounds__(256) void k_contrastive(const float* __restrict__ img,
                                                     const float* __restrict__ sent,
                                                     const float* __restrict__ comp,
                                                     const float* __restrict__ rel,
                                                     const int*   __restrict__ relidx,
                                                     float* __restrict__ ws) {
    const int t  = blockIdx.z;
    const int i0 = blockIdx.y * 16, j0 = blockIdx.x * 16;
    const int tid = threadIdx.x, ty = tid >> 4, tx = tid & 15;
    __shared__ float As[16][68];
    __shared__ float Bs[16][68];
    __shared__ float red[4];

    // B-row pointer for the staged row (row index = ty)
    const int j_row = j0 + ty;
    const float* brow;
    if (t == 0)      brow = sent + (size_t)j_row * DD;
    else if (t == 1) brow = comp + (size_t)j_row * DD;
    else             brow = rel + ((size_t)j_row * PRR + relidx[j_row]) * DD;
    const float* arow = img + (size_t)(i0 + ty) * DD;

    float acc = 0.0f;
    for (int kc = 0; kc < DD; kc += 64) {
        __syncthreads();
        // stage: each thread one float4 of A and one of B (16 rows x 16 quads)
        float4 va = *reinterpret_cast<const float4*>(arow + kc + tx * 4);
        float4 vb = *reinterpret_cast<const float4*>(brow + kc + tx * 4);
        *reinterpret_cast<float4*>(&As[ty][tx * 4]) = va;
        *reinterpret_cast<float4*>(&Bs[ty][tx * 4]) = vb;
        __syncthreads();
#pragma unroll 8
        for (int d = 0; d < 64; ++d)
            acc += As[ty][d] * Bs[tx][d];
    }

    const int i = i0 + ty, j = j0 + tx;
    const float diag_i = ws[WS_DIAG + t * BB + i];
    const float diag_j = ws[WS_DIAG + t * BB + j];
    float contrib = 0.0f;
    if (i != j) {
        contrib = fmaxf(acc - diag_i, 0.0f);          // cost_s
        if (t < 2) contrib += fmaxf(acc - diag_j, 0.0f); // cost_im (not for rel)
    }
#pragma unroll
    for (int off = 32; off > 0; off >>= 1) contrib += __shfl_down(contrib, off);
    if ((tid & 63) == 0) red[tid >> 6] = contrib;
    __syncthreads();
    if (tid == 0) {
        const int slot = (t == 0) ? 4 : (t == 1) ? 3 : 2;  // sent/comp/rel
        atomicAdd(&ws[slot], red[0] + red[1] + red[2] + red[3]);
    }
}

// global_loss for rel: grid(512) = (b,p); 64 threads
__global__ __launch_bounds__(64) void k_globalrel(const float* __restrict__ img,
                                                  const float* __restrict__ rel,
                                                  const float* __restrict__ negrel,
                                                  float* __restrict__ ws) {
    const int blk = blockIdx.x, b = blk >> 2, p = blk & 3;
    const int lane = threadIdx.x;
    const float* a = img + (size_t)b * DD;
    float4 ir[4];
#pragma unroll
    for (int k = 0; k < 4; ++k)
        ir[k] = *reinterpret_cast<const float4*>(a + lane * 4 + k * 256);

    auto dotv = [&](const float* __restrict__ v) -> float {
        float acc = 0.0f;
#pragma unroll
        for (int k = 0; k < 4; ++k) {
            float4 w = *reinterpret_cast<const float4*>(v + lane * 4 + k * 256);
            acc += ir[k].x * w.x + ir[k].y * w.y + ir[k].z * w.z + ir[k].w * w.w;
        }
#pragma unroll
        for (int off = 32; off > 0; off >>= 1) acc += __shfl_xor(acc, off);
        return acc;  // all lanes hold the result
    };

    float pos = dotv(rel + ((size_t)b * PRR + p) * DD);
    float mx = -1e30f;
    const float* nb = negrel + ((size_t)b * PRR + p) * NNEG * DD;
    for (int n = 0; n < NNEG; ++n) mx = fmaxf(mx, dotv(nb + (size_t)n * DD));
    if (lane == 0) atomicAdd(&ws[2], fmaxf(mx - pos, 0.0f));
}

// local_loss: grid (2, 128, 3) = (p-half, b, loss-type); 256 threads
// Per block: GEMM [68 rows = 4 pos + 64 neg] x [36 img_feat rows] over K=1024,
// then max-over-n + softmax-weighted hinge epilogue.
__global__ __launch_bounds__(256) void k_local(const float* __restrict__ feat,
                                               const float* __restrict__ obj,
                                               const float* __restrict__ attr,
                                               const float* __restrict__ nobj,
                                               const float* __restrict__ nattrn,
                                               const float* __restrict__ nattra,
                                               float* __restrict__ ws) {
    const int ph = blockIdx.x;   // 0/1 -> p in [ph*4, ph*4+4)
    const int b  = blockIdx.y;
    const int t  = blockIdx.z;   // 0:obj 1:attr(n) 2:attr(a)
    const int tid = threadIdx.x;

    const float* pos = (t == 0) ? obj : attr;
    const float* neg = (t == 0) ? nobj : (t == 1) ? nattrn : nattra;

    const float* posb = pos + ((size_t)b * PP + ph * 4) * DD;          // 4 rows
    const float* negb = neg + ((size_t)b * PP + ph * 4) * NNEG * DD;   // 64 rows
    const float* fb   = feat + (size_t)b * RR * DD;                    // 36 rows

    __shared__ float Vs[68][68];   // 68 rows x 64-chunk (+4 pad, 16B-aligned stride)
    __shared__ float Fs[36][68];
    __shared__ float S[68][37];    // full score tile for epilogue
    __shared__ float hin[4][36];
    __shared__ float sm[4][36];

    // thread tile: active tid<204: ty=tid/12 (17), tx=tid%12 (12)
    const int ty = tid / 12, tx = tid % 12;
    const bool act = (tid < 204);

    float acc[4][3];
#pragma unroll
    for (int m = 0; m < 4; ++m)
#pragma unroll
        for (int nn = 0; nn < 3; ++nn) acc[m][nn] = 0.0f;

    for (int kc = 0; kc < DD; kc += 64) {
        __syncthreads();
        // stage V: 68 rows x 16 float4
        for (int i = tid; i < 68 * 16; i += 256) {
            const int row = i >> 4, q = i & 15;
            const float* src = (row < 4) ? (posb + (size_t)row * DD)
                                         : (negb + (size_t)(row - 4) * DD);
            *reinterpret_cast<float4*>(&Vs[row][q * 4]) =
                *reinterpret_cast<const float4*>(src + kc + q * 4);
        }
        // stage F: 36 rows x 16 float4
        for (int i = tid; i < 36 * 16; i += 256) {
            const int row = i >> 4, q = i & 15;
            *reinterpret_cast<float4*>(&Fs[row][q * 4]) =
                *reinterpret_cast<const float4*>(fb + (size_t)row * DD + kc + q * 4);
        }
        __syncthreads();
        if (act) {
#pragma unroll 4
            for (int d4 = 0; d4 < 16; ++d4) {
                const float4 f0 = *reinterpret_cast<const float4*>(&Fs[tx][d4 * 4]);
                const float4 f1 = *reinterpret_cast<const float4*>(&Fs[tx + 12][d4 * 4]);
                const float4 f2 = *reinterpret_cast<const float4*>(&Fs[tx + 24][d4 * 4]);
#pragma unroll
                for (int m = 0; m < 4; ++m) {
                    const float4 v = *reinterpret_cast<const float4*>(&Vs[ty + 17 * m][d4 * 4]);
                    acc[m][0] += v.x * f0.x + v.y * f0.y + v.z * f0.z + v.w * f0.w;
                    acc[m][1] += v.x * f1.x + v.y * f1.y + v.z * f1.z + v.w * f1.w;
                    acc[m][2] += v.x * f2.x + v.y * f2.y + v.z * f2.z + v.w * f2.w;
                }
            }
        }
    }
    __syncthreads();
    if (act) {
#pragma unroll
        for (int m = 0; m < 4; ++m)
#pragma unroll
            for (int nn = 0; nn < 3; ++nn)
                S[ty + 17 * m][tx + 12 * nn] = acc[m][nn];
    }
    __syncthreads();

    // epilogue: rows 0..3 = pos sims; rows 4+16*pl+n = neg
    if (tid < 144) {
        const int pl = tid / 36, r = tid % 36;
        const float s = S[pl][r];
        float mx = -1e30f;
#pragma unroll
        for (int n = 0; n < NNEG; ++n) mx = fmaxf(mx, S[4 + pl * 16 + n][r]);
        hin[pl][r] = fmaxf(mx - s, 0.0f);
        sm[pl][r]  = s;
    }
    __syncthreads();
    if (tid < 4) {
        const int pl = tid;
        float mx = -1e30f;
        for (int r = 0; r < RR; ++r) mx = fmaxf(mx, sm[pl][r]);
        float den = 0.0f, num = 0.0f;
        for (int r = 0; r < RR; ++r) {
            const float e = __expf(sm[pl][r] - mx);
            den += e;
            num += e * hin[pl][r];
        }
        atomicAdd(&ws[(t == 0) ? 0 : 1], num / den);
    }
}

__global__ __launch_bounds__(64) void k_final(const float* __restrict__ ws,
                                              float* __restrict__ out) {
    if (threadIdx.x == 0) {
        const float obj = ws[0], attr = ws[1], rel = ws[2], comp = ws[3], sent = ws[4];
        out[0] = sent + 0.5f * comp + 0.5f * rel + 0.5f * attr + 0.5f * obj;
        out[1] = obj;
        out[2] = attr;
        out[3] = rel;
        out[4] = comp;
        out[5] = sent;
    }
}

extern "C" void kernel_launch(void* const* d_in, const int* in_sizes, int n_in,
                              void* d_out, int out_size, void* d_ws, size_t ws_size,
                              hipStream_t stream) {
    const float* img    = (const float*)d_in[0];
    const float* sent   = (const float*)d_in[1];
    const float* comp   = (const float*)d_in[2];
    const float* feat   = (const float*)d_in[3];
    const float* obj    = (const float*)d_in[4];
    const float* nobj   = (const float*)d_in[5];
    const float* attr   = (const float*)d_in[6];
    const float* nattrn = (const float*)d_in[7];
    const float* nattra = (const float*)d_in[8];
    const float* rel    = (const float*)d_in[9];
    const float* nrel   = (const float*)d_in[10];
    const int*   relidx = (const int*)d_in[11];
    float* ws  = (float*)d_ws;
    float* out = (float*)d_out;

    k_zero<<<dim3(1), dim3(64), 0, stream>>>(ws);
    k_diag<<<dim3(BB, 3), dim3(64), 0, stream>>>(img, sent, comp, rel, relidx, ws);
    k_contrastive<<<dim3(8, 8, 3), dim3(256), 0, stream>>>(img, sent, comp, rel, relidx, ws);
    k_globalrel<<<dim3(BB * PRR), dim3(64), 0, stream>>>(img, rel, nrel, ws);
    k_local<<<dim3(2, BB, 3), dim3(256), 0, stream>>>(feat, obj, attr, nobj, nattrn, nattra, ws);
    k_final<<<dim3(1), dim3(64), 0, stream>>>(ws, out);
}

// Round 2
// 116.606 us; speedup vs baseline: 1.6581x; 1.6581x over previous
//
#include <hip/hip_runtime.h>

#define BB   128
#define DD   1024
#define RR   36
#define PP   8
#define NNEG 16
#define PRR  4

typedef __bf16 bf16x8 __attribute__((ext_vector_type(8)));
typedef __bf16 bf16x4 __attribute__((ext_vector_type(4)));
typedef float f32x4 __attribute__((ext_vector_type(4)));

// ws float layout: [0]=obj [1]=attr [2]=rel [3]=comp [4]=sent ; [16..400)=diag[3][128]
#define WS_DIAG 16

__global__ __launch_bounds__(64) void k_zero(float* __restrict__ ws) {
    int t = threadIdx.x;
    if (t < 8) ws[t] = 0.0f;
}

__global__ __launch_bounds__(64) void k_diag(const float* __restrict__ img,
                                             const float* __restrict__ sent,
                                             const float* __restrict__ comp,
                                             const float* __restrict__ rel,
                                             const int*   __restrict__ relidx,
                                             float* __restrict__ ws) {
    const int i = blockIdx.x, t = blockIdx.y, lane = threadIdx.x;
    const float* x;
    if (t == 0)      x = sent + (size_t)i * DD;
    else if (t == 1) x = comp + (size_t)i * DD;
    else             x = rel + ((size_t)i * PRR + relidx[i]) * DD;
    const float* a = img + (size_t)i * DD;
    float acc = 0.0f;
#pragma unroll
    for (int k = 0; k < 4; ++k) {
        float4 va = *reinterpret_cast<const float4*>(a + lane * 4 + k * 256);
        float4 vb = *reinterpret_cast<const float4*>(x + lane * 4 + k * 256);
        acc += va.x * vb.x + va.y * vb.y + va.z * vb.z + va.w * vb.w;
    }
#pragma unroll
    for (int off = 32; off > 0; off >>= 1) acc += __shfl_down(acc, off);
    if (lane == 0) ws[WS_DIAG + t * BB + i] = acc;
}

// scores tile (16x16) per block; grid (8,8,3); 256 threads = 16x16
__global__ __launch_bounds__(256) void k_contrastive(const float* __restrict__ img,
                                                     const float* __restrict__ sent,
                                                     const float* __restrict__ comp,
                                                     const float* __restrict__ rel,
                                                     const int*   __restrict__ relidx,
                                                     float* __restrict__ ws) {
    const int t  = blockIdx.z;
    const int i0 = blockIdx.y * 16, j0 = blockIdx.x * 16;
    const int tid = threadIdx.x, ty = tid >> 4, tx = tid & 15;
    __shared__ float As[16][68];
    __shared__ float Bs[16][68];
    __shared__ float red[4];

    const int j_row = j0 + ty;
    const float* brow;
    if (t == 0)      brow = sent + (size_t)j_row * DD;
    else if (t == 1) brow = comp + (size_t)j_row * DD;
    else             brow = rel + ((size_t)j_row * PRR + relidx[j_row]) * DD;
    const float* arow = img + (size_t)(i0 + ty) * DD;

    float acc = 0.0f;
    for (int kc = 0; kc < DD; kc += 64) {
        __syncthreads();
        float4 va = *reinterpret_cast<const float4*>(arow + kc + tx * 4);
        float4 vb = *reinterpret_cast<const float4*>(brow + kc + tx * 4);
        *reinterpret_cast<float4*>(&As[ty][tx * 4]) = va;
        *reinterpret_cast<float4*>(&Bs[ty][tx * 4]) = vb;
        __syncthreads();
#pragma unroll 8
        for (int d = 0; d < 64; ++d)
            acc += As[ty][d] * Bs[tx][d];
    }

    const int i = i0 + ty, j = j0 + tx;
    const float diag_i = ws[WS_DIAG + t * BB + i];
    const float diag_j = ws[WS_DIAG + t * BB + j];
    float contrib = 0.0f;
    if (i != j) {
        contrib = fmaxf(acc - diag_i, 0.0f);             // cost_s
        if (t < 2) contrib += fmaxf(acc - diag_j, 0.0f); // cost_im (not for rel)
    }
#pragma unroll
    for (int off = 32; off > 0; off >>= 1) contrib += __shfl_down(contrib, off);
    if ((tid & 63) == 0) red[tid >> 6] = contrib;
    __syncthreads();
    if (tid == 0) {
        const int slot = (t == 0) ? 4 : (t == 1) ? 3 : 2;  // sent/comp/rel
        atomicAdd(&ws[slot], red[0] + red[1] + red[2] + red[3]);
    }
}

// global_loss for rel: grid(512) = (b,p); 64 threads
__global__ __launch_bounds__(64) void k_globalrel(const float* __restrict__ img,
                                                  const float* __restrict__ rel,
                                                  const float* __restrict__ negrel,
                                                  float* __restrict__ ws) {
    const int blk = blockIdx.x, b = blk >> 2, p = blk & 3;
    const int lane = threadIdx.x;
    const float* a = img + (size_t)b * DD;
    float4 ir[4];
#pragma unroll
    for (int k = 0; k < 4; ++k)
        ir[k] = *reinterpret_cast<const float4*>(a + lane * 4 + k * 256);

    auto dotv = [&](const float* __restrict__ v) -> float {
        float acc = 0.0f;
#pragma unroll
        for (int k = 0; k < 4; ++k) {
            float4 w = *reinterpret_cast<const float4*>(v + lane * 4 + k * 256);
            acc += ir[k].x * w.x + ir[k].y * w.y + ir[k].z * w.z + ir[k].w * w.w;
        }
#pragma unroll
        for (int off = 32; off > 0; off >>= 1) acc += __shfl_xor(acc, off);
        return acc;
    };

    float pos = dotv(rel + ((size_t)b * PRR + p) * DD);
    float mx = -1e30f;
    const float* nb = negrel + ((size_t)b * PRR + p) * NNEG * DD;
    for (int n = 0; n < NNEG; ++n) mx = fmaxf(mx, dotv(nb + (size_t)n * DD));
    if (lane == 0) atomicAdd(&ws[2], fmaxf(mx - pos, 0.0f));
}

// local_loss via bf16 MFMA: grid (3 t, 128 b); 512 threads = 8 waves, wave = p.
// Per wave: M-tile = the 16 negatives of (b,t,p) (A-frags straight from global,
// fp32->bf16 in regs) x N = 36 feat rows (padded to 48, bf16 in LDS), K=1024.
// A second broadcast A-frag (pos row) yields pos sims in the same pass.
__global__ __launch_bounds__(512) void k_local2(const float* __restrict__ feat,
                                                const float* __restrict__ obj,
                                                const float* __restrict__ attr,
                                                const float* __restrict__ nobj,
                                                const float* __restrict__ nattrn,
                                                const float* __restrict__ nattra,
                                                float* __restrict__ ws) {
    const int t = blockIdx.x;   // 0:obj 1:attr(n) 2:attr(a)
    const int b = blockIdx.y;
    const int tid = threadIdx.x;
    const int wv = tid >> 6;    // = p
    const int lane = tid & 63;
    const int lrow = lane & 15;
    const int kg = (lane >> 4) * 8;

    const float* pos = (t == 0) ? obj : attr;
    const float* neg = (t == 0) ? nobj : (t == 1) ? nattrn : nattra;
    const float* posb = pos + ((size_t)b * PP + wv) * DD;
    const float* negb = neg + ((size_t)(b * PP + wv) * NNEG) * DD;
    const float* fb   = feat + (size_t)b * RR * DD;

    // feat staged as bf16, rows padded to 48 (rows>=36 zero), stride 520 (2-way bank = free)
    __shared__ __attribute__((aligned(16))) __bf16 Fs[48][520];

    f32x4 accn[3], accp[3];
#pragma unroll
    for (int nt = 0; nt < 3; ++nt) {
        accn[nt] = (f32x4){0.f, 0.f, 0.f, 0.f};
        accp[nt] = (f32x4){0.f, 0.f, 0.f, 0.f};
    }

    for (int kc = 0; kc < DD; kc += 512) {
        __syncthreads();
        // stage: 48 rows x 128 quads of 4 elems
        for (int i = tid; i < 48 * 128; i += 512) {
            const int row = i >> 7, q = i & 127;
            bf16x4 w;
            if (row < RR) {
                float4 v = *reinterpret_cast<const float4*>(fb + (size_t)row * DD + kc + q * 4);
                w[0] = (__bf16)v.x; w[1] = (__bf16)v.y; w[2] = (__bf16)v.z; w[3] = (__bf16)v.w;
            } else {
                w[0] = (__bf16)0.f; w[1] = (__bf16)0.f; w[2] = (__bf16)0.f; w[3] = (__bf16)0.f;
            }
            *reinterpret_cast<bf16x4*>(&Fs[row][q * 4]) = w;
        }
        __syncthreads();

        for (int ks = 0; ks < 16; ++ks) {
            const int kbase = kc + ks * 32 + kg;
            const int lk = ks * 32 + kg;
            // A (neg) fragment: row = lane&15, 8 contiguous k
            const float* aptr = negb + (size_t)lrow * DD + kbase;
            float4 n0 = *reinterpret_cast<const float4*>(aptr);
            float4 n1 = *reinterpret_cast<const float4*>(aptr + 4);
            // A (pos) broadcast fragment
            const float* pptr = posb + kbase;
            float4 p0 = *reinterpret_cast<const float4*>(pptr);
            float4 p1 = *reinterpret_cast<const float4*>(pptr + 4);
            bf16x8 an, ap;
            an[0] = (__bf16)n0.x; an[1] = (__bf16)n0.y; an[2] = (__bf16)n0.z; an[3] = (__bf16)n0.w;
            an[4] = (__bf16)n1.x; an[5] = (__bf16)n1.y; an[6] = (__bf16)n1.z; an[7] = (__bf16)n1.w;
            ap[0] = (__bf16)p0.x; ap[1] = (__bf16)p0.y; ap[2] = (__bf16)p0.z; ap[3] = (__bf16)p0.w;
            ap[4] = (__bf16)p1.x; ap[5] = (__bf16)p1.y; ap[6] = (__bf16)p1.z; ap[7] = (__bf16)p1.w;
#pragma unroll
            for (int nt = 0; nt < 3; ++nt) {
                bf16x8 bt = *reinterpret_cast<const bf16x8*>(&Fs[nt * 16 + lrow][lk]);
                accn[nt] = __builtin_amdgcn_mfma_f32_16x16x32_bf16(an, bt, accn[nt], 0, 0, 0);
                accp[nt] = __builtin_amdgcn_mfma_f32_16x16x32_bf16(ap, bt, accp[nt], 0, 0, 0);
            }
        }
    }

    // epilogue (register-only): col = lane&15 within tile nt -> r = nt*16 + col
    float s3[3], h3[3];
#pragma unroll
    for (int nt = 0; nt < 3; ++nt) {
        f32x4 a = accn[nt];
        float m = fmaxf(fmaxf(a[0], a[1]), fmaxf(a[2], a[3]));
        m = fmaxf(m, __shfl_xor(m, 16));
        m = fmaxf(m, __shfl_xor(m, 32));            // max over the 16 neg rows
        float s = accp[nt][0];                      // pos sim (all rows identical)
        s3[nt] = s;
        h3[nt] = fmaxf(m - s, 0.0f);
    }
    // softmax over r (36 valid cols spread over lanes 0..15 x 3 tiles)
    float mx = -1e30f;
#pragma unroll
    for (int nt = 0; nt < 3; ++nt)
        if (nt * 16 + lrow < RR) mx = fmaxf(mx, s3[nt]);
#pragma unroll
    for (int off = 1; off < 16; off <<= 1) mx = fmaxf(mx, __shfl_xor(mx, off));
    float den = 0.0f, num = 0.0f;
#pragma unroll
    for (int nt = 0; nt < 3; ++nt)
        if (nt * 16 + lrow < RR) {
            float e = __expf(s3[nt] - mx);
            den += e;
            num += e * h3[nt];
        }
#pragma unroll
    for (int off = 1; off < 16; off <<= 1) {
        den += __shfl_xor(den, off);
        num += __shfl_xor(num, off);
    }
    if (lane == 0) atomicAdd(&ws[(t == 0) ? 0 : 1], num / den);
}

__global__ __launch_bounds__(64) void k_final(const float* __restrict__ ws,
                                              float* __restrict__ out) {
    if (threadIdx.x == 0) {
        const float obj = ws[0], attr = ws[1], rel = ws[2], comp = ws[3], sent = ws[4];
        out[0] = sent + 0.5f * comp + 0.5f * rel + 0.5f * attr + 0.5f * obj;
        out[1] = obj;
        out[2] = attr;
        out[3] = rel;
        out[4] = comp;
        out[5] = sent;
    }
}

extern "C" void kernel_launch(void* const* d_in, const int* in_sizes, int n_in,
                              void* d_out, int out_size, void* d_ws, size_t ws_size,
                              hipStream_t stream) {
    const float* img    = (const float*)d_in[0];
    const float* sent   = (const float*)d_in[1];
    const float* comp   = (const float*)d_in[2];
    const float* feat   = (const float*)d_in[3];
    const float* obj    = (const float*)d_in[4];
    const float* nobj   = (const float*)d_in[5];
    const float* nattrn = (const float*)d_in[6 + 1];
    const float* attr   = (const float*)d_in[6];
    const float* nattra = (const float*)d_in[8];
    const float* rel    = (const float*)d_in[9];
    const float* nrel   = (const float*)d_in[10];
    const int*   relidx = (const int*)d_in[11];
    float* ws  = (float*)d_ws;
    float* out = (float*)d_out;

    k_zero<<<dim3(1), dim3(64), 0, stream>>>(ws);
    k_diag<<<dim3(BB, 3), dim3(64), 0, stream>>>(img, sent, comp, rel, relidx, ws);
    k_contrastive<<<dim3(8, 8, 3), dim3(256), 0, stream>>>(img, sent, comp, rel, relidx, ws);
    k_globalrel<<<dim3(BB * PRR), dim3(64), 0, stream>>>(img, rel, nrel, ws);
    k_local2<<<dim3(3, BB), dim3(512), 0, stream>>>(feat, obj, attr, nobj, nattrn, nattra, ws);
    k_final<<<dim3(1), dim3(64), 0, stream>>>(ws, out);
}

// Round 3
// 100.370 us; speedup vs baseline: 1.9263x; 1.1618x over previous
//
#include <hip/hip_runtime.h>

#define BB   128
#define DD   1024
#define RR   36
#define PP   8
#define NNEG 16
#define PRR  4

typedef __bf16 bf16x8 __attribute__((ext_vector_type(8)));
typedef float f32x4 __attribute__((ext_vector_type(4)));

// ws float layout: [0]=obj [1]=attr [2]=rel [3]=comp [4]=sent ; [16..400)=diag[3][128]
// byte 4096+: bf16 feat fragments [b][nt(3)][ks(32)][lane(64)][8]
#define WS_DIAG 16
#define WSF_OFF_BYTES 4096
#define WSF_PER_B (3 * 32 * 64 * 8)  // bf16 elems per b
#define WSF_BYTES ((size_t)WSF_OFF_BYTES + (size_t)BB * WSF_PER_B * 2)

__global__ __launch_bounds__(64) void k_zero(float* __restrict__ ws) {
    int t = threadIdx.x;
    if (t < 8) ws[t] = 0.0f;
}

__global__ __launch_bounds__(64) void k_diag(const float* __restrict__ img,
                                             const float* __restrict__ sent,
                                             const float* __restrict__ comp,
                                             const float* __restrict__ rel,
                                             const int*   __restrict__ relidx,
                                             float* __restrict__ ws) {
    const int i = blockIdx.x, t = blockIdx.y, lane = threadIdx.x;
    const float* x;
    if (t == 0)      x = sent + (size_t)i * DD;
    else if (t == 1) x = comp + (size_t)i * DD;
    else             x = rel + ((size_t)i * PRR + relidx[i]) * DD;
    const float* a = img + (size_t)i * DD;
    float acc = 0.0f;
#pragma unroll
    for (int k = 0; k < 4; ++k) {
        float4 va = *reinterpret_cast<const float4*>(a + lane * 4 + k * 256);
        float4 vb = *reinterpret_cast<const float4*>(x + lane * 4 + k * 256);
        acc += va.x * vb.x + va.y * vb.y + va.z * vb.z + va.w * vb.w;
    }
#pragma unroll
    for (int off = 32; off > 0; off >>= 1) acc += __shfl_down(acc, off);
    if (lane == 0) ws[WS_DIAG + t * BB + i] = acc;
}

// scores tile (16x16) per block; grid (8,8,3); 256 threads = 16x16
__global__ __launch_bounds__(256) void k_contrastive(const float* __restrict__ img,
                                                     const float* __restrict__ sent,
                                                     const float* __restrict__ comp,
                                                     const float* __restrict__ rel,
                                                     const int*   __restrict__ relidx,
                                                     float* __restrict__ ws) {
    const int t  = blockIdx.z;
    const int i0 = blockIdx.y * 16, j0 = blockIdx.x * 16;
    const int tid = threadIdx.x, ty = tid >> 4, tx = tid & 15;
    __shared__ float As[16][68];
    __shared__ float Bs[16][68];
    __shared__ float red[4];

    const int j_row = j0 + ty;
    const float* brow;
    if (t == 0)      brow = sent + (size_t)j_row * DD;
    else if (t == 1) brow = comp + (size_t)j_row * DD;
    else             brow = rel + ((size_t)j_row * PRR + relidx[j_row]) * DD;
    const float* arow = img + (size_t)(i0 + ty) * DD;

    float acc = 0.0f;
    for (int kc = 0; kc < DD; kc += 64) {
        __syncthreads();
        float4 va = *reinterpret_cast<const float4*>(arow + kc + tx * 4);
        float4 vb = *reinterpret_cast<const float4*>(brow + kc + tx * 4);
        *reinterpret_cast<float4*>(&As[ty][tx * 4]) = va;
        *reinterpret_cast<float4*>(&Bs[ty][tx * 4]) = vb;
        __syncthreads();
#pragma unroll 8
        for (int d = 0; d < 64; ++d)
            acc += As[ty][d] * Bs[tx][d];
    }

    const int i = i0 + ty, j = j0 + tx;
    const float diag_i = ws[WS_DIAG + t * BB + i];
    const float diag_j = ws[WS_DIAG + t * BB + j];
    float contrib = 0.0f;
    if (i != j) {
        contrib = fmaxf(acc - diag_i, 0.0f);             // cost_s
        if (t < 2) contrib += fmaxf(acc - diag_j, 0.0f); // cost_im (not for rel)
    }
#pragma unroll
    for (int off = 32; off > 0; off >>= 1) contrib += __shfl_down(contrib, off);
    if ((tid & 63) == 0) red[tid >> 6] = contrib;
    __syncthreads();
    if (tid == 0) {
        const int slot = (t == 0) ? 4 : (t == 1) ? 3 : 2;  // sent/comp/rel
        atomicAdd(&ws[slot], red[0] + red[1] + red[2] + red[3]);
    }
}

// global_loss for rel: grid(512) = (b,p); 64 threads
__global__ __launch_bounds__(64) void k_globalrel(const float* __restrict__ img,
                                                  const float* __restrict__ rel,
                                                  const float* __restrict__ negrel,
                                                  float* __restrict__ ws) {
    const int blk = blockIdx.x, b = blk >> 2, p = blk & 3;
    const int lane = threadIdx.x;
    const float* a = img + (size_t)b * DD;
    float4 ir[4];
#pragma unroll
    for (int k = 0; k < 4; ++k)
        ir[k] = *reinterpret_cast<const float4*>(a + lane * 4 + k * 256);

    auto dotv = [&](const float* __restrict__ v) -> float {
        float acc = 0.0f;
#pragma unroll
        for (int k = 0; k < 4; ++k) {
            float4 w = *reinterpret_cast<const float4*>(v + lane * 4 + k * 256);
            acc += ir[k].x * w.x + ir[k].y * w.y + ir[k].z * w.z + ir[k].w * w.w;
        }
#pragma unroll
        for (int off = 32; off > 0; off >>= 1) acc += __shfl_xor(acc, off);
        return acc;
    };

    float pos = dotv(rel + ((size_t)b * PRR + p) * DD);
    float mx = -1e30f;
    const float* nb = negrel + ((size_t)b * PRR + p) * NNEG * DD;
    for (int n = 0; n < NNEG; ++n) mx = fmaxf(mx, dotv(nb + (size_t)n * DD));
    if (lane == 0) atomicAdd(&ws[2], fmaxf(mx - pos, 0.0f));
}

// Pre-convert feat to bf16 in MFMA B-fragment layout: [b][nt][ks][lane]x8,
// where lane encodes (col r = nt*16 + (lane&15), k-sub (lane>>4)*8).
__global__ __launch_bounds__(256) void k_featcvt(const float* __restrict__ feat,
                                                 __bf16* __restrict__ wsf) {
    const int b = blockIdx.x, nt = blockIdx.y, tid = threadIdx.x;
    const float* fb = feat + (size_t)b * RR * DD;
    __bf16* ob = wsf + (size_t)b * WSF_PER_B + (size_t)nt * 32 * 64 * 8;
    for (int i = tid; i < 32 * 64; i += 256) {
        const int ks = i >> 6, lane = i & 63;
        const int r = nt * 16 + (lane & 15);
        const int k0 = ks * 32 + (lane >> 4) * 8;
        bf16x8 w;
        if (r < RR) {
            float4 v0 = *reinterpret_cast<const float4*>(fb + (size_t)r * DD + k0);
            float4 v1 = *reinterpret_cast<const float4*>(fb + (size_t)r * DD + k0 + 4);
            w[0] = (__bf16)v0.x; w[1] = (__bf16)v0.y; w[2] = (__bf16)v0.z; w[3] = (__bf16)v0.w;
            w[4] = (__bf16)v1.x; w[5] = (__bf16)v1.y; w[6] = (__bf16)v1.z; w[7] = (__bf16)v1.w;
        } else {
#pragma unroll
            for (int j = 0; j < 8; ++j) w[j] = (__bf16)0.0f;
        }
        *reinterpret_cast<bf16x8*>(ob + (size_t)i * 8) = w;
    }
}

// local_loss via bf16 MFMA, no LDS, depth-1 register pipeline.
// grid (3 t, 128 b, 2 p-half); 256 threads = 4 waves; wave = p = z*4+wv.
template <bool WSFEAT>
__global__ __launch_bounds__(256) void k_local3(const float* __restrict__ feat,
                                                const float* __restrict__ obj,
                                                const float* __restrict__ attr,
                                                const float* __restrict__ nobj,
                                                const float* __restrict__ nattrn,
                                                const float* __restrict__ nattra,
                                                const __bf16* __restrict__ wsf,
                                                float* __restrict__ ws) {
    const int t = blockIdx.x;   // 0:obj 1:attr(n) 2:attr(a)
    const int b = blockIdx.y;
    const int tid = threadIdx.x;
    const int wv = tid >> 6;
    const int p = blockIdx.z * 4 + wv;
    const int lane = tid & 63;
    const int lrow = lane & 15;
    const int kgq = lane >> 4;          // k-sub-group, *8 for element offset

    const float* pos = (t == 0) ? obj : attr;
    const float* neg = (t == 0) ? nobj : (t == 1) ? nattrn : nattra;
    const float* posb = pos + ((size_t)b * PP + p) * DD + kgq * 8;
    const float* negb = neg + ((size_t)(b * PP + p) * NNEG + lrow) * DD + kgq * 8;
    const float* fb   = feat + (size_t)b * RR * DD;
    const __bf16* wfb = wsf + (size_t)b * WSF_PER_B + (size_t)lane * 8;

    f32x4 accn[3], accp[3];
#pragma unroll
    for (int nt = 0; nt < 3; ++nt) {
        accn[nt] = (f32x4){0.f, 0.f, 0.f, 0.f};
        accp[nt] = (f32x4){0.f, 0.f, 0.f, 0.f};
    }

    auto LOAD = [&](int ks, float4& n0, float4& n1, float4& p0, float4& p1, bf16x8* f) {
        const float* np = negb + ks * 32;
        n0 = *reinterpret_cast<const float4*>(np);
        n1 = *reinterpret_cast<const float4*>(np + 4);
        const float* pp = posb + ks * 32;
        p0 = *reinterpret_cast<const float4*>(pp);
        p1 = *reinterpret_cast<const float4*>(pp + 4);
        if (WSFEAT) {
#pragma unroll
            for (int nt = 0; nt < 3; ++nt)
                f[nt] = *reinterpret_cast<const bf16x8*>(wfb + ((size_t)(nt * 32 + ks)) * 512);
        } else {
#pragma unroll
            for (int nt = 0; nt < 3; ++nt) {
                const int r = nt * 16 + lrow;
                if (r < RR) {
                    const float* fp = fb + (size_t)r * DD + ks * 32 + kgq * 8;
                    float4 v0 = *reinterpret_cast<const float4*>(fp);
                    float4 v1 = *reinterpret_cast<const float4*>(fp + 4);
                    f[nt][0] = (__bf16)v0.x; f[nt][1] = (__bf16)v0.y;
                    f[nt][2] = (__bf16)v0.z; f[nt][3] = (__bf16)v0.w;
                    f[nt][4] = (__bf16)v1.x; f[nt][5] = (__bf16)v1.y;
                    f[nt][6] = (__bf16)v1.z; f[nt][7] = (__bf16)v1.w;
                } else {
#pragma unroll
                    for (int j = 0; j < 8; ++j) f[nt][j] = (__bf16)0.0f;
                }
            }
        }
    };

    float4 cn0, cn1, cp0, cp1;
    bf16x8 cf[3];
    LOAD(0, cn0, cn1, cp0, cp1, cf);

#pragma unroll
    for (int ks = 0; ks < 32; ++ks) {
        float4 nn0 = cn0, nn1 = cn1, np0 = cp0, np1 = cp1;
        bf16x8 nf[3] = {cf[0], cf[1], cf[2]};
        if (ks + 1 < 32) LOAD(ks + 1, nn0, nn1, np0, np1, nf);

        bf16x8 an, ap;
        an[0] = (__bf16)cn0.x; an[1] = (__bf16)cn0.y; an[2] = (__bf16)cn0.z; an[3] = (__bf16)cn0.w;
        an[4] = (__bf16)cn1.x; an[5] = (__bf16)cn1.y; an[6] = (__bf16)cn1.z; an[7] = (__bf16)cn1.w;
        ap[0] = (__bf16)cp0.x; ap[1] = (__bf16)cp0.y; ap[2] = (__bf16)cp0.z; ap[3] = (__bf16)cp0.w;
        ap[4] = (__bf16)cp1.x; ap[5] = (__bf16)cp1.y; ap[6] = (__bf16)cp1.z; ap[7] = (__bf16)cp1.w;

#pragma unroll
        for (int nt = 0; nt < 3; ++nt) {
            accn[nt] = __builtin_amdgcn_mfma_f32_16x16x32_bf16(an, cf[nt], accn[nt], 0, 0, 0);
            accp[nt] = __builtin_amdgcn_mfma_f32_16x16x32_bf16(ap, cf[nt], accp[nt], 0, 0, 0);
        }
        cn0 = nn0; cn1 = nn1; cp0 = np0; cp1 = np1;
        cf[0] = nf[0]; cf[1] = nf[1]; cf[2] = nf[2];
    }

    // epilogue: col = lane&15 within tile nt -> r = nt*16 + col
    float s3[3], h3[3];
#pragma unroll
    for (int nt = 0; nt < 3; ++nt) {
        f32x4 a = accn[nt];
        float m = fmaxf(fmaxf(a[0], a[1]), fmaxf(a[2], a[3]));
        m = fmaxf(m, __shfl_xor(m, 16));
        m = fmaxf(m, __shfl_xor(m, 32));   // max over the 16 neg rows
        float s = accp[nt][0];             // pos sim (all rows identical)
        s3[nt] = s;
        h3[nt] = fmaxf(m - s, 0.0f);
    }
    float mx = -1e30f;
#pragma unroll
    for (int nt = 0; nt < 3; ++nt)
        if (nt * 16 + lrow < RR) mx = fmaxf(mx, s3[nt]);
#pragma unroll
    for (int off = 1; off < 16; off <<= 1) mx = fmaxf(mx, __shfl_xor(mx, off));
    float den = 0.0f, num = 0.0f;
#pragma unroll
    for (int nt = 0; nt < 3; ++nt)
        if (nt * 16 + lrow < RR) {
            float e = __expf(s3[nt] - mx);
            den += e;
            num += e * h3[nt];
        }
#pragma unroll
    for (int off = 1; off < 16; off <<= 1) {
        den += __shfl_xor(den, off);
        num += __shfl_xor(num, off);
    }

    __shared__ float red[4];
    if (lane == 0) red[wv] = num / den;
    __syncthreads();
    if (tid == 0)
        atomicAdd(&ws[(t == 0) ? 0 : 1], red[0] + red[1] + red[2] + red[3]);
}

__global__ __launch_bounds__(64) void k_final(const float* __restrict__ ws,
                                              float* __restrict__ out) {
    if (threadIdx.x == 0) {
        const float obj = ws[0], attr = ws[1], rel = ws[2], comp = ws[3], sent = ws[4];
        out[0] = sent + 0.5f * comp + 0.5f * rel + 0.5f * attr + 0.5f * obj;
        out[1] = obj;
        out[2] = attr;
        out[3] = rel;
        out[4] = comp;
        out[5] = sent;
    }
}

extern "C" void kernel_launch(void* const* d_in, const int* in_sizes, int n_in,
                              void* d_out, int out_size, void* d_ws, size_t ws_size,
                              hipStream_t stream) {
    const float* img    = (const float*)d_in[0];
    const float* sent   = (const float*)d_in[1];
    const float* comp   = (const float*)d_in[2];
    const float* feat   = (const float*)d_in[3];
    const float* obj    = (const float*)d_in[4];
    const float* nobj   = (const float*)d_in[5];
    const float* attr   = (const float*)d_in[6];
    const float* nattrn = (const float*)d_in[7];
    const float* nattra = (const float*)d_in[8];
    const float* rel    = (const float*)d_in[9];
    const float* nrel   = (const float*)d_in[10];
    const int*   relidx = (const int*)d_in[11];
    float* ws  = (float*)d_ws;
    float* out = (float*)d_out;
    __bf16* wsf = (__bf16*)((char*)d_ws + WSF_OFF_BYTES);

    const bool usewsf = (ws_size >= WSF_BYTES);

    k_zero<<<dim3(1), dim3(64), 0, stream>>>(ws);
    k_diag<<<dim3(BB, 3), dim3(64), 0, stream>>>(img, sent, comp, rel, relidx, ws);
    k_contrastive<<<dim3(8, 8, 3), dim3(256), 0, stream>>>(img, sent, comp, rel, relidx, ws);
    k_globalrel<<<dim3(BB * PRR), dim3(64), 0, stream>>>(img, rel, nrel, ws);
    if (usewsf) {
        k_featcvt<<<dim3(BB, 3), dim3(256), 0, stream>>>(feat, wsf);
        k_local3<true><<<dim3(3, BB, 2), dim3(256), 0, stream>>>(feat, obj, attr, nobj, nattrn,
                                                                 nattra, wsf, ws);
    } else {
        k_local3<false><<<dim3(3, BB, 2), dim3(256), 0, stream>>>(feat, obj, attr, nobj, nattrn,
                                                                  nattra, wsf, ws);
    }
    k_final<<<dim3(1), dim3(64), 0, stream>>>(ws, out);
}